// Round 3
// baseline (29251.279 us; speedup 1.0000x reference)
//
#include <hip/hip_runtime.h>
#include <math.h>

#define Tn 64
#define Bn 32
#define INn 64
#define Nn 512
#define WDn 64
#define Rn 4
#define Hn 256
#define G4H 1024
#define OUTn 64
#define IFn 471
#define CTRLn 320
#define KTOT 576
#define CLIPV 20.0f
#define EPSV 1e-6f

#define OFF_RKEY 0
#define OFF_RSTR 256
#define OFF_WKEY 260
#define OFF_WSTR 324
#define OFF_ERASE 325
#define OFF_WVEC 389
#define OFF_FREE 453
#define OFF_AG 457
#define OFF_WG 458
#define OFF_MODES 459

// ---------------- persistent device state ----------------
__device__ float S_h[2][Bn][Hn];          // h(t) in slot t&1
__device__ float S_c[2][Bn][Hn];
__device__ float S_mem[Bn][Nn][WDn];
__device__ float S_rw[Bn][Rn][Nn];        // rw(t) written by finalize(t)
__device__ float S_ww[2][Bn][Nn];         // ww(t) in slot t&1
__device__ float S_link[Bn][Nn][Nn];
__device__ float S_prec[2][Bn][Nn];       // prec(t) in slot t&1
__device__ float S_usage[2][Bn][Nn];      // usage(t) in slot t&1
__device__ float S_reads[Bn][Rn][WDn];
__device__ float S_itf[Bn][IFn];
__device__ float S_rc[Bn][Rn][Nn];
__device__ float S_fw[Bn][Rn][Nn];
__device__ float S_bwp[Bn][8][Rn*Nn];     // per-chunk bw partials
__device__ float S_sumww[Bn];
__device__ unsigned int g_linkdone[Bn];
__device__ unsigned int g_fincount;

// ---------------- helpers ----------------
__device__ __forceinline__ float sigm(float x){ return 1.f/(1.f+expf(-x)); }
__device__ __forceinline__ float clipv(float x){ return fminf(fmaxf(x,-CLIPV),CLIPV); }
__device__ __forceinline__ float oneplusf(float x){
  float sp = (x > 0.f) ? (x + log1pf(expf(-x))) : log1pf(expf(x));
  return 1.f + sp;
}
__device__ __forceinline__ float wredsum(float v){
  #pragma unroll
  for (int o=32;o>0;o>>=1) v += __shfl_xor(v,o,64);
  return v;
}
__device__ __forceinline__ float bredsum(float v, volatile float* scr){
  v = wredsum(v);
  if ((threadIdx.x & 63) == 0) scr[threadIdx.x >> 6] = v;
  __syncthreads();
  float s = scr[0];
  #pragma unroll
  for (int i=1;i<8;i++) s += scr[i];
  __syncthreads();
  return s;
}
__device__ __forceinline__ float bredmax(float v, volatile float* scr){
  #pragma unroll
  for (int o=32;o>0;o>>=1) v = fmaxf(v,__shfl_xor(v,o,64));
  if ((threadIdx.x & 63) == 0) scr[threadIdx.x >> 6] = v;
  __syncthreads();
  float m = scr[0];
  #pragma unroll
  for (int i=1;i<8;i++) m = fmaxf(m, scr[i]);
  __syncthreads();
  return m;
}

// ================= init =================
extern "C" __global__ void __launch_bounds__(256)
k_init(){
  size_t g = (size_t)blockIdx.x*256 + threadIdx.x;
  size_t stride = (size_t)gridDim.x*256;
  float* lk = &S_link[0][0][0];
  for (size_t i=g; i<(size_t)Bn*Nn*Nn; i+=stride) lk[i]=0.f;
  float* mm = &S_mem[0][0][0];
  for (size_t i=g; i<(size_t)Bn*Nn*WDn; i+=stride) mm[i]=0.f;
  float* rr = &S_rw[0][0][0];
  for (size_t i=g; i<(size_t)Bn*Rn*Nn; i+=stride) rr[i]=0.f;
  float* rd = &S_reads[0][0][0];
  for (size_t i=g; i<(size_t)Bn*Rn*WDn; i+=stride) rd[i]=0.f;
  for (size_t i=g; i<(size_t)2*Bn*Nn; i+=stride){
    S_ww[0][0][i]=0.f; S_prec[0][0][i]=0.f; S_usage[0][0][i]=0.f;
  }
  for (size_t i=g; i<(size_t)2*Bn*Hn; i+=stride){
    S_h[0][0][i]=0.f; S_c[0][0][i]=0.f;
  }
  if (blockIdx.x==0 && threadIdx.x < Bn) g_linkdone[threadIdx.x]=0u;
  if (blockIdx.x==0 && threadIdx.x == 0) g_fincount=0u;
}

// ================= gates stage (shared by prologue + D2) =================
struct ShG { float ctrl[Bn][65]; };

__device__ __forceinline__ void gates_stage(ShG& sg, int tn,
        const float* __restrict__ xin, const float* __restrict__ Wx,
        const float* __restrict__ Wh, const float* __restrict__ b_lstm){
  const int tid = threadIdx.x;
  const int hs = tid >> 5, b = tid & 31;
  const int h = (blockIdx.x >= 288 ? (int)blockIdx.x - 288 : (int)blockIdx.x)*16 + hs;
  const int hp = (tn+1)&1;    // slot of h(tn-1)
  float a0=b_lstm[h], a1=b_lstm[Hn+h], a2=b_lstm[2*Hn+h], a3=b_lstm[3*Hn+h];
  for (int c=0;c<9;++c){
    // stage chunk k in [c*64, c*64+64) for all 32 batches
    #pragma unroll
    for (int u=0;u<4;u++){
      int e = u*512 + tid;
      int b2 = e >> 6, kk = e & 63;
      float v;
      if (c==0)       v = xin[((size_t)tn*Bn + b2)*INn + kk];
      else if (c<5)   v = ((const float*)S_reads[b2])[(c-1)*64 + kk];
      else            v = S_h[hp][b2][(c-5)*64 + kk];
      sg.ctrl[b2][kk] = v;
    }
    __syncthreads();
    const float* wbase = (c<5) ? (Wx + (size_t)(c*64)*G4H) : (Wh + (size_t)((c-5)*64)*G4H);
    #pragma unroll
    for (int kk=0;kk<64;kk++){
      float cv = sg.ctrl[b][kk];
      const float* w = wbase + (size_t)kk*G4H;
      a0 += cv*w[h]; a1 += cv*w[Hn+h]; a2 += cv*w[2*Hn+h]; a3 += cv*w[3*Hn+h];
    }
    __syncthreads();
  }
  float cold = S_c[hp][b][h];
  float cn = sigm(a1)*cold + sigm(a0)*tanhf(a2);
  float hn = sigm(a3)*tanhf(cn);
  S_c[tn&1][b][h] = clipv(cn);
  S_h[tn&1][b][h] = clipv(hn);
}

extern "C" __global__ void __launch_bounds__(512)
k_gates_pro(const float* __restrict__ xin, const float* __restrict__ Wx,
            const float* __restrict__ Wh, const float* __restrict__ b_lstm){
  __shared__ ShG sg;
  gates_stage(sg, 0, xin, Wx, Wh, b_lstm);
}

// ================= D1: per-batch phase A =================
struct ShA {
  float hc[Hn];
  float itf[IFn];
  unsigned long long keys[Nn];
  float alloc[Nn];
  float sim[Nn];
  float rsim[Rn][Nn];
  float tile[64][65];
  float wkey[WDn];
  float rk[Rn][WDn];
  float er[WDn];
  float wv[WDn];
  float red[8];
  float knw, knr[Rn], betar[Rn];
};
extern "C" __global__ void __launch_bounds__(512, 2)
k_phaseA(int t, const float* __restrict__ W_if, const float* __restrict__ b_if){
  __shared__ ShA sh;
  const int tid = threadIdx.x;
  const int lane = tid & 63, wvi = tid >> 6;
  const int b = blockIdx.x;
  const int cur = t&1, prev = cur^1;
  if (tid < Hn) sh.hc[tid] = S_h[cur][b][tid];
  __syncthreads();
  // itf = hc @ W_if + b_if  (unroll-8 for load pipelining)
  if (tid < IFn){
    float acc = b_if[tid];
    for (int k=0;k<Hn;k+=8){
      float s = 0.f;
      #pragma unroll
      for (int u=0;u<8;u++) s += sh.hc[k+u]*W_if[(size_t)(k+u)*IFn + tid];
      acc += s;
    }
    sh.itf[tid] = acc;
    S_itf[b][tid] = acc;
  }
  __syncthreads();
  if (tid < WDn){
    sh.wkey[tid] = sh.itf[OFF_WKEY+tid];
    sh.er[tid]   = sigm(sh.itf[OFF_ERASE+tid]);
    sh.wv[tid]   = sh.itf[OFF_WVEC+tid];
  } else if (tid < WDn + Rn*WDn){
    int k2 = tid - WDn;
    sh.rk[k2>>6][k2&63] = sh.itf[OFF_RKEY + k2];
  }
  // usage update + stable-sort key (all 512 threads, n = tid)
  {
    float fg0=sigm(sh.itf[OFF_FREE+0]), fg1=sigm(sh.itf[OFF_FREE+1]);
    float fg2=sigm(sh.itf[OFF_FREE+2]), fg3=sigm(sh.itf[OFF_FREE+3]);
    int n = tid;
    float uu = S_usage[prev][b][n], wwp = S_ww[prev][b][n];
    float u = uu + (1.f-uu)*wwp;
    float psi = (1.f - fg0*S_rw[b][0][n])*(1.f - fg1*S_rw[b][1][n])
              * (1.f - fg2*S_rw[b][2][n])*(1.f - fg3*S_rw[b][3][n]);
    float un = u*psi;
    S_usage[cur][b][n] = un;
    float v = EPSV + (1.f-EPSV)*un;
    sh.keys[n] = ((unsigned long long)__float_as_uint(v) << 32) | (unsigned)n;
  }
  __syncthreads();
  // key norms
  if (wvi==0){
    float kv = sh.wkey[lane];
    float s2 = wredsum(kv*kv);
    if (lane==0) sh.knw = sqrtf(s2);
  } else if (wvi<=4){
    int r = wvi-1;
    float kv = sh.rk[r][lane];
    float s2 = wredsum(kv*kv);
    if (lane==0) sh.knr[r] = sqrtf(s2);
  } else if (wvi==5 && lane<4){
    sh.betar[lane] = oneplusf(sh.itf[OFF_RSTR+lane]);
  }
  // sort-free allocation: a_i = (1-u_i) * prod_{key_j < key_i} u_j
  {
    unsigned long long myk = sh.keys[tid];
    float prod = 1.f;
    for (int j=0;j<Nn;j+=8){
      #pragma unroll
      for (int u=0;u<8;u++){
        unsigned long long kj = sh.keys[j+u];
        float uj = __uint_as_float((unsigned)(kj>>32));
        prod *= (kj < myk) ? uj : 1.f;
      }
    }
    float myu = __uint_as_float((unsigned)(myk>>32));
    sh.alloc[tid] = (1.f - myu)*prod;
  }
  __syncthreads();
  // write-content sims over OLD mem (tile-transpose pattern)
  float betaw = oneplusf(sh.itf[OFF_WSTR]);
  for (int tile=0;tile<8;tile++){
    #pragma unroll
    for (int u=0;u<8;u++){
      int e = u*512 + tid;
      int nn = e>>6, w = e&63;
      sh.tile[nn][w] = S_mem[b][tile*64+nn][w];
    }
    __syncthreads();
    {
      int nn = tid>>3, qq = tid&7;
      float d=0.f, nrm=0.f;
      #pragma unroll
      for (int i=0;i<8;i++){
        int w = qq*8+i;
        float m = sh.tile[nn][w];
        d += m*sh.wkey[w]; nrm += m*m;
      }
      #pragma unroll
      for (int o=1;o<8;o<<=1){ d += __shfl_xor(d,o,64); nrm += __shfl_xor(nrm,o,64); }
      if (qq==0){
        int n = tile*64+nn;
        sh.sim[n] = betaw * d / (sh.knw*sqrtf(nrm) + EPSV);
      }
    }
    __syncthreads();
  }
  // softmax(sim) -> wc ; ww ; sumww
  {
    float v = sh.sim[tid];
    float mx = bredmax(v, sh.red);
    float e = expf(v - mx);
    float ssum = bredsum(e, sh.red);
    float wc = e/ssum;
    float ag = sigm(sh.itf[OFF_AG]);
    float wg = sigm(sh.itf[OFF_WG]);
    float wwv = wg*(ag*sh.alloc[tid] + (1.f-ag)*wc);
    S_ww[cur][b][tid] = wwv;
    float wsum = bredsum(wwv, sh.red);
    if (tid==0) S_sumww[b] = wsum;
    sh.alloc[tid] = wwv;         // alloc now holds ww
  }
  __syncthreads();
  // mem erase/write + read-content sims on NEW mem
  for (int tile=0;tile<8;tile++){
    #pragma unroll
    for (int u=0;u<8;u++){
      int e = u*512 + tid;
      int nn = e>>6, w = e&63;
      int n = tile*64+nn;
      float m = S_mem[b][n][w];
      float wwn = sh.alloc[n];
      m = m*(1.f - wwn*sh.er[w]) + wwn*sh.wv[w];
      S_mem[b][n][w] = m;
      sh.tile[nn][w] = m;
    }
    __syncthreads();
    {
      int nn = tid>>3, qq = tid&7;
      float a0=0.f,a1=0.f,a2=0.f,a3=0.f,nrm=0.f;
      #pragma unroll
      for (int i=0;i<8;i++){
        int w = qq*8+i;
        float m = sh.tile[nn][w];
        a0 += m*sh.rk[0][w]; a1 += m*sh.rk[1][w];
        a2 += m*sh.rk[2][w]; a3 += m*sh.rk[3][w];
        nrm += m*m;
      }
      #pragma unroll
      for (int o=1;o<8;o<<=1){
        a0 += __shfl_xor(a0,o,64); a1 += __shfl_xor(a1,o,64);
        a2 += __shfl_xor(a2,o,64); a3 += __shfl_xor(a3,o,64);
        nrm += __shfl_xor(nrm,o,64);
      }
      if (qq==0){
        int n = tile*64+nn;
        float mn = sqrtf(nrm);
        sh.rsim[0][n] = sh.betar[0]*a0/(sh.knr[0]*mn + EPSV);
        sh.rsim[1][n] = sh.betar[1]*a1/(sh.knr[1]*mn + EPSV);
        sh.rsim[2][n] = sh.betar[2]*a2/(sh.knr[2]*mn + EPSV);
        sh.rsim[3][n] = sh.betar[3]*a3/(sh.knr[3]*mn + EPSV);
      }
    }
    __syncthreads();
  }
  // rc softmax per head
  for (int r=0;r<Rn;r++){
    float v = sh.rsim[r][tid];
    float mx = bredmax(v, sh.red);
    float e = expf(v - mx);
    float ssum = bredsum(e, sh.red);
    S_rc[b][r][tid] = e/ssum;
  }
}

// ================= D2: link (256 blk) + finalize (32 blk) + gates (16 blk) ==
struct ShL {
  float ww[Nn];
  float prec[Nn];
  float rw[Rn][Nn];
  float bwp4[4][Rn][Nn];
};
struct ShF {
  float fw[Rn][Nn];
  float bw[Rn][Nn];
  float rc[Rn][Nn];       // becomes rw after combine
  float modes[Rn][4];
  float part[8][Rn][WDn];
  float vin[512];
};
union ShD { ShL l; ShF f; ShG g; };

extern "C" __global__ void __launch_bounds__(512, 4)
k_linkfin(int t, const float* __restrict__ xin,
          const float* __restrict__ Wx, const float* __restrict__ Wh,
          const float* __restrict__ b_lstm,
          const float* __restrict__ W_out, const float* __restrict__ b_out,
          float* __restrict__ outp){
  __shared__ ShD sh;
  const int tid = threadIdx.x;
  const int lane = tid & 63, wvi = tid >> 6;
  const int bid = blockIdx.x;
  const int cur = t&1, prev = cur^1;

  if (bid < 256){
    // ---------- link role ----------
    const int b = bid >> 3, ch = bid & 7;
    const int i0 = ch*64;
    sh.l.ww[tid]   = S_ww[cur][b][tid];
    sh.l.prec[tid] = S_prec[prev][b][tid];
    for (int k=tid;k<Rn*Nn;k+=512) ((float*)sh.l.rw)[k] = ((const float*)S_rw[b])[k];
    __syncthreads();
    float sumww = S_sumww[b];
    // per-lane j-groups: j = jjc*256 + lane*4 + s
    float wj[2][4], pj[2][4], rj[4][2][4];
    #pragma unroll
    for (int jjc=0;jjc<2;jjc++){
      float4 w4 = ((const float4*)sh.l.ww)[jjc*64+lane];
      float4 p4 = ((const float4*)sh.l.prec)[jjc*64+lane];
      wj[jjc][0]=w4.x; wj[jjc][1]=w4.y; wj[jjc][2]=w4.z; wj[jjc][3]=w4.w;
      pj[jjc][0]=p4.x; pj[jjc][1]=p4.y; pj[jjc][2]=p4.z; pj[jjc][3]=p4.w;
      #pragma unroll
      for (int r=0;r<4;r++){
        float4 r4 = ((const float4*)sh.l.rw[r])[jjc*64+lane];
        rj[r][jjc][0]=r4.x; rj[r][jjc][1]=r4.y; rj[r][jjc][2]=r4.z; rj[r][jjc][3]=r4.w;
      }
    }
    float bwa[4][2][4];
    #pragma unroll
    for (int r=0;r<4;r++)
      #pragma unroll
      for (int jjc=0;jjc<2;jjc++)
        #pragma unroll
        for (int s=0;s<4;s++) bwa[r][jjc][s]=0.f;
    for (int rr=0;rr<8;rr++){
      const int i = i0 + wvi*8 + rr;
      float wi = sh.l.ww[i];
      float ci = 1.f - wi;
      float ri[4] = {sh.l.rw[0][i], sh.l.rw[1][i], sh.l.rw[2][i], sh.l.rw[3][i]};
      float f[4] = {0.f,0.f,0.f,0.f};
      float4* lrow4 = (float4*)(&S_link[b][i][0]);
      #pragma unroll
      for (int jjc=0;jjc<2;jjc++){
        float4 L4 = lrow4[jjc*64+lane];
        float Ls[4] = {L4.x, L4.y, L4.z, L4.w};
        #pragma unroll
        for (int s=0;s<4;s++){
          float Ln = (ci - wj[jjc][s])*Ls[s] + wi*pj[jjc][s];
          int j = jjc*256 + lane*4 + s;
          Ln = (j==i) ? 0.f : Ln;
          Ls[s] = Ln;
          #pragma unroll
          for (int r=0;r<4;r++){
            f[r] += Ln*rj[r][jjc][s];
            bwa[r][jjc][s] += Ln*ri[r];
          }
        }
        float4 Lo; Lo.x=Ls[0]; Lo.y=Ls[1]; Lo.z=Ls[2]; Lo.w=Ls[3];
        lrow4[jjc*64+lane] = Lo;
      }
      #pragma unroll
      for (int r=0;r<4;r++){
        float fr = wredsum(f[r]);
        if (lane==0) S_fw[b][r][i] = fr;
      }
    }
    // cross-wave bw reduce (deterministic)
    if (wvi < 4){
      #pragma unroll
      for (int r=0;r<4;r++)
        #pragma unroll
        for (int jjc=0;jjc<2;jjc++){
          float4 v4; v4.x=bwa[r][jjc][0]; v4.y=bwa[r][jjc][1]; v4.z=bwa[r][jjc][2]; v4.w=bwa[r][jjc][3];
          ((float4*)sh.l.bwp4[wvi][r])[jjc*64+lane] = v4;
        }
    }
    __syncthreads();
    if (wvi >= 4){
      int v = wvi-4;
      #pragma unroll
      for (int r=0;r<4;r++)
        #pragma unroll
        for (int jjc=0;jjc<2;jjc++){
          float4 v4 = ((float4*)sh.l.bwp4[v][r])[jjc*64+lane];
          v4.x+=bwa[r][jjc][0]; v4.y+=bwa[r][jjc][1]; v4.z+=bwa[r][jjc][2]; v4.w+=bwa[r][jjc][3];
          ((float4*)sh.l.bwp4[v][r])[jjc*64+lane] = v4;
        }
    }
    __syncthreads();
    for (int k=tid;k<Rn*Nn;k+=512){
      float s = ((float*)sh.l.bwp4[0])[k] + ((float*)sh.l.bwp4[1])[k]
              + ((float*)sh.l.bwp4[2])[k] + ((float*)sh.l.bwp4[3])[k];
      S_bwp[b][ch][k] = s;
    }
    if (tid < 64){
      int j = i0 + tid;
      S_prec[cur][b][j] = (1.f - sumww)*sh.l.prec[j] + sh.l.ww[j];
    }
    __syncthreads();
    if (tid==0){
      __builtin_amdgcn_fence(__ATOMIC_RELEASE, "agent");
      __hip_atomic_fetch_add(&g_linkdone[b], 1u, __ATOMIC_RELAXED, __HIP_MEMORY_SCOPE_AGENT);
    }
  } else if (bid < 288){
    // ---------- finalize role ----------
    const int b = bid - 256;
    if (tid==0){
      while (__hip_atomic_load(&g_linkdone[b], __ATOMIC_RELAXED, __HIP_MEMORY_SCOPE_AGENT) < 8u*(unsigned)(t+1))
        __builtin_amdgcn_s_sleep(32);
      __builtin_amdgcn_fence(__ATOMIC_ACQUIRE, "agent");
    }
    __syncthreads();
    for (int k=tid;k<Rn*Nn;k+=512){
      ((float*)sh.f.fw)[k] = ((const float*)S_fw[b])[k];
      float sbw = 0.f;
      #pragma unroll
      for (int ch=0;ch<8;ch++) sbw += S_bwp[b][ch][k];
      ((float*)sh.f.bw)[k] = sbw;
      ((float*)sh.f.rc)[k] = ((const float*)S_rc[b])[k];
    }
    if (tid < 4){
      int r = tid;
      float m0 = S_itf[b][OFF_MODES + r*3 + 0];
      float m1 = S_itf[b][OFF_MODES + r*3 + 1];
      float m2 = S_itf[b][OFF_MODES + r*3 + 2];
      float mx = fmaxf(m0,fmaxf(m1,m2));
      float e0=expf(m0-mx), e1=expf(m1-mx), e2=expf(m2-mx);
      float si = e0+e1+e2;
      sh.f.modes[r][0]=e0/si; sh.f.modes[r][1]=e1/si; sh.f.modes[r][2]=e2/si;
    }
    __syncthreads();
    // rw = cm*rc + fm*fw + bm*bw
    for (int k=tid;k<Rn*Nn;k+=512){
      int r = k>>9, n = k&511;
      float v = sh.f.modes[r][2]*sh.f.rc[r][n] + sh.f.modes[r][1]*sh.f.fw[r][n]
              + sh.f.modes[r][0]*sh.f.bw[r][n];
      sh.f.rc[r][n] = v;
      S_rw[b][r][n] = v;
    }
    __syncthreads();
    // reads = rw @ mem
    {
      float a0=0.f,a1=0.f,a2=0.f,a3=0.f;
      #pragma unroll 4
      for (int nn=0;nn<64;nn++){
        int n = wvi*64+nn;
        float m = S_mem[b][n][lane];
        a0 += sh.f.rc[0][n]*m; a1 += sh.f.rc[1][n]*m;
        a2 += sh.f.rc[2][n]*m; a3 += sh.f.rc[3][n]*m;
      }
      sh.f.part[wvi][0][lane]=a0; sh.f.part[wvi][1][lane]=a1;
      sh.f.part[wvi][2][lane]=a2; sh.f.part[wvi][3][lane]=a3;
    }
    __syncthreads();
    if (tid < 256){
      int r = tid>>6, w = tid&63;
      float sv = 0.f;
      #pragma unroll
      for (int v=0;v<8;v++) sv += sh.f.part[v][r][w];
      S_reads[b][r][w] = sv;
      sh.f.vin[256+tid] = sv;
      sh.f.vin[tid] = S_h[cur][b][tid];
    }
    __syncthreads();
    // out = clip([hc, reads] @ W_out + b_out)  (8 K-slices of 64)
    {
      int qq = tid>>6, o = tid&63;
      float sacc = 0.f;
      for (int k2=qq*64;k2<qq*64+64;k2+=8){
        #pragma unroll
        for (int u=0;u<8;u++) sacc += sh.f.vin[k2+u]*W_out[(size_t)(k2+u)*OUTn + o];
      }
      sh.f.part[qq][0][o] = sacc;
    }
    __syncthreads();
    if (tid < 64){
      float sv = b_out[tid];
      #pragma unroll
      for (int qq=0;qq<8;qq++) sv += sh.f.part[qq][0][tid];
      outp[((size_t)t*Bn + b)*OUTn + tid] = clipv(sv);
    }
    __syncthreads();
    if (tid==0){
      __builtin_amdgcn_fence(__ATOMIC_RELEASE, "agent");
      __hip_atomic_fetch_add(&g_fincount, 1u, __ATOMIC_RELAXED, __HIP_MEMORY_SCOPE_AGENT);
    }
  } else {
    // ---------- gates role (compute h/c for step t+1) ----------
    if (t+1 >= Tn) return;
    if (tid==0){
      while (__hip_atomic_load(&g_fincount, __ATOMIC_RELAXED, __HIP_MEMORY_SCOPE_AGENT) < 32u*(unsigned)(t+1))
        __builtin_amdgcn_s_sleep(32);
      __builtin_amdgcn_fence(__ATOMIC_ACQUIRE, "agent");
    }
    __syncthreads();
    gates_stage(sh.g, t+1, xin, Wx, Wh, b_lstm);
  }
}

extern "C" void kernel_launch(void* const* d_in, const int* in_sizes, int n_in,
                              void* d_out, int out_size, void* d_ws, size_t ws_size,
                              hipStream_t stream){
  (void)in_sizes; (void)n_in; (void)d_ws; (void)ws_size; (void)out_size;
  const float* xin = (const float*)d_in[0];
  const float* Wx  = (const float*)d_in[1];
  const float* Wh  = (const float*)d_in[2];
  const float* bl  = (const float*)d_in[3];
  const float* Wif = (const float*)d_in[4];
  const float* bif = (const float*)d_in[5];
  const float* Wo  = (const float*)d_in[6];
  const float* bo  = (const float*)d_in[7];
  hipLaunchKernelGGL(k_init, dim3(1024), dim3(256), 0, stream);
  hipLaunchKernelGGL(k_gates_pro, dim3(16), dim3(512), 0, stream, xin, Wx, Wh, bl);
  for (int t=0; t<Tn; ++t){
    hipLaunchKernelGGL(k_phaseA,  dim3(32),  dim3(512), 0, stream, t, Wif, bif);
    hipLaunchKernelGGL(k_linkfin, dim3(304), dim3(512), 0, stream, t, xin, Wx, Wh, bl, Wo, bo, (float*)d_out);
  }
}

// Round 4
// 7154.342 us; speedup vs baseline: 4.0886x; 4.0886x over previous
//
#include <hip/hip_runtime.h>
#include <math.h>

#define Tn 64
#define Bn 32
#define INn 64
#define Nn 512
#define WDn 64
#define Rn 4
#define Hn 256
#define G4H 1024
#define OUTn 64
#define IFn 471
#define CLIPV 20.0f
#define EPSV 1e-6f

#define OFF_RKEY 0
#define OFF_RSTR 256
#define OFF_WKEY 260
#define OFF_WSTR 324
#define OFF_ERASE 325
#define OFF_WVEC 389
#define OFF_FREE 453
#define OFF_AG 457
#define OFF_WG 458
#define OFF_MODES 459

// ---------------- persistent device state ----------------
__device__ float S_h[2][Bn][Hn];          // h(t) in slot t&1 (written by phaseA(t))
__device__ float S_c[2][Bn][Hn];
__device__ float S_gates[2][Bn][G4H];     // raw gates(t) in slot t&1 (written by gates role of dispatch t-1)
__device__ float S_mem[Bn][Nn][WDn];
__device__ float S_rw[Bn][Rn][Nn];        // rw(t) written by finalize(t)
__device__ float S_ww[2][Bn][Nn];
__device__ float S_link[Bn][Nn][Nn];
__device__ float S_prec[2][Bn][Nn];
__device__ float S_usage[2][Bn][Nn];
__device__ float S_reads[Bn][Rn][WDn];
__device__ float S_itf[Bn][IFn];
__device__ float S_rc[Bn][Rn][Nn];
__device__ float S_fw[Bn][Rn][Nn];
__device__ float S_bwp[Bn][8][Rn*Nn];
__device__ float S_sumww[Bn];
__device__ unsigned int g_ww[Bn];         // phaseA(t) done up to ww  -> t+1
__device__ unsigned int g_rc[Bn];         // phaseA(t) fully done     -> t+1
__device__ unsigned int g_ld[Bn];         // link chunks done         -> 8*(t+1)
__device__ unsigned int g_fin;            // finalize blocks done     -> 32*(t+1)

// ---------------- helpers ----------------
__device__ __forceinline__ float sigm(float x){ return 1.f/(1.f+expf(-x)); }
__device__ __forceinline__ float clipv(float x){ return fminf(fmaxf(x,-CLIPV),CLIPV); }
__device__ __forceinline__ float oneplusf(float x){
  float sp = (x > 0.f) ? (x + log1pf(expf(-x))) : log1pf(expf(x));
  return 1.f + sp;
}
__device__ __forceinline__ float wredsum(float v){
  #pragma unroll
  for (int o=32;o>0;o>>=1) v += __shfl_xor(v,o,64);
  return v;
}
__device__ __forceinline__ float bredsum(float v, volatile float* scr){
  v = wredsum(v);
  if ((threadIdx.x & 63) == 0) scr[threadIdx.x >> 6] = v;
  __syncthreads();
  float s = scr[0];
  #pragma unroll
  for (int i=1;i<8;i++) s += scr[i];
  __syncthreads();
  return s;
}
__device__ __forceinline__ float bredmax(float v, volatile float* scr){
  #pragma unroll
  for (int o=32;o>0;o>>=1) v = fmaxf(v,__shfl_xor(v,o,64));
  if ((threadIdx.x & 63) == 0) scr[threadIdx.x >> 6] = v;
  __syncthreads();
  float m = scr[0];
  #pragma unroll
  for (int i=1;i<8;i++) m = fmaxf(m, scr[i]);
  __syncthreads();
  return m;
}
__device__ __forceinline__ void sig_release(unsigned int* flag){
  __builtin_amdgcn_fence(__ATOMIC_RELEASE, "agent");
  __hip_atomic_fetch_add(flag, 1u, __ATOMIC_RELAXED, __HIP_MEMORY_SCOPE_AGENT);
}
__device__ __forceinline__ void spin_until(unsigned int* flag, unsigned int target){
  while (__hip_atomic_load(flag, __ATOMIC_RELAXED, __HIP_MEMORY_SCOPE_AGENT) < target)
    __builtin_amdgcn_s_sleep(8);
}

// ================= init =================
extern "C" __global__ void __launch_bounds__(256)
k_init(){
  size_t g = (size_t)blockIdx.x*256 + threadIdx.x;
  size_t stride = (size_t)gridDim.x*256;
  float* lk = &S_link[0][0][0];
  for (size_t i=g; i<(size_t)Bn*Nn*Nn; i+=stride) lk[i]=0.f;
  float* mm = &S_mem[0][0][0];
  for (size_t i=g; i<(size_t)Bn*Nn*WDn; i+=stride) mm[i]=0.f;
  float* rr = &S_rw[0][0][0];
  for (size_t i=g; i<(size_t)Bn*Rn*Nn; i+=stride) rr[i]=0.f;
  float* rd = &S_reads[0][0][0];
  for (size_t i=g; i<(size_t)Bn*Rn*WDn; i+=stride) rd[i]=0.f;
  for (size_t i=g; i<(size_t)2*Bn*Nn; i+=stride){
    S_ww[0][0][i]=0.f; S_prec[0][0][i]=0.f; S_usage[0][0][i]=0.f;
  }
  for (size_t i=g; i<(size_t)2*Bn*Hn; i+=stride){
    S_h[0][0][i]=0.f; S_c[0][0][i]=0.f;
  }
  if (blockIdx.x==0){
    if (threadIdx.x < Bn){ g_ww[threadIdx.x]=0u; g_rc[threadIdx.x]=0u; g_ld[threadIdx.x]=0u; }
    if (threadIdx.x == 0) g_fin=0u;
  }
}

// ================= gates GEMM core (coalesced j-tile, 4 batches/wave) ======
struct ShG { float ctrl[Bn][65]; };

__device__ __forceinline__ void gates_core(ShG& sg, int tn, int jt,
        const float* __restrict__ xin, const float* __restrict__ Wx,
        const float* __restrict__ Wh, const float* __restrict__ b_lstm){
  const int tid = threadIdx.x, lane = tid & 63, wvi = tid >> 6;
  const int j = jt*64 + lane;
  const int hp = (tn+1)&1;        // slot of h(tn-1)
  const int b0 = wvi*4;           // this wave's 4 batches
  float bias = b_lstm[j];
  float a0=bias, a1=bias, a2=bias, a3=bias;
  for (int c=0;c<9;++c){
    #pragma unroll
    for (int u=0;u<4;u++){
      int e = u*512 + tid;
      int b2 = e >> 6, kk = e & 63;
      float v;
      if (c==0)       v = xin[((size_t)tn*Bn + b2)*INn + kk];
      else if (c<5)   v = ((const float*)S_reads[b2])[(c-1)*64 + kk];
      else            v = S_h[hp][b2][(c-5)*64 + kk];
      sg.ctrl[b2][kk] = v;
    }
    __syncthreads();
    const float* wb = (c<5) ? (Wx + (size_t)(c*64)*G4H + j)
                            : (Wh + (size_t)((c-5)*64)*G4H + j);
    #pragma unroll
    for (int kk=0;kk<64;kk++){
      float wv = wb[(size_t)kk*G4H];
      a0 += sg.ctrl[b0+0][kk]*wv;
      a1 += sg.ctrl[b0+1][kk]*wv;
      a2 += sg.ctrl[b0+2][kk]*wv;
      a3 += sg.ctrl[b0+3][kk]*wv;
    }
    __syncthreads();
  }
  const int gs = tn&1;
  S_gates[gs][b0+0][j]=a0;
  S_gates[gs][b0+1][j]=a1;
  S_gates[gs][b0+2][j]=a2;
  S_gates[gs][b0+3][j]=a3;
}

extern "C" __global__ void __launch_bounds__(512)
k_gates_pro(const float* __restrict__ xin, const float* __restrict__ Wx,
            const float* __restrict__ Wh, const float* __restrict__ b_lstm){
  __shared__ ShG sg;
  gates_core(sg, 0, blockIdx.x, xin, Wx, Wh, b_lstm);
}

// ================= shared-mem role layouts =================
struct ShA {
  float hc[Hn];
  float itf[IFn];
  unsigned long long keys[Nn];
  float alloc[Nn];
  float sim[Nn];
  float rsim[Rn][Nn];
  float tile[64][65];
  float wkey[WDn];
  float rk[Rn][WDn];
  float er[WDn];
  float wv[WDn];
  float red[8];
  float knw, knr[Rn], betar[Rn];
};
struct ShL {
  float ww[Nn];
  float prec[Nn];
  float rw[Rn][Nn];
  float bwp4[4][Rn][Nn];
};
struct ShF {
  float fw[Rn][Nn];
  float bw[Rn][Nn];
  float rc[Rn][Nn];
  float modes[Rn][4];
  float part[8][Rn][WDn];
  float vin[512];
};
union ShU { ShA a; ShL l; ShF f; ShG g; };

// ================= the per-step kernel: 336 blocks x 512 =================
extern "C" __global__ void __launch_bounds__(512, 4)
k_step(int t, const float* __restrict__ xin,
       const float* __restrict__ Wx, const float* __restrict__ Wh,
       const float* __restrict__ b_lstm,
       const float* __restrict__ W_if, const float* __restrict__ b_if,
       const float* __restrict__ W_out, const float* __restrict__ b_out,
       float* __restrict__ outp){
  __shared__ ShU sh;
  const int tid = threadIdx.x;
  const int lane = tid & 63, wvi = tid >> 6;
  const int bid = blockIdx.x;
  const int cur = t&1, prev = cur^1;

  if (bid < 32){
    // ================= phaseA =================
    const int b = bid;
    // LSTM combine from raw gates (computed last dispatch)
    if (tid < Hn){
      int h = tid;
      float g0=S_gates[cur][b][h],     g1=S_gates[cur][b][Hn+h];
      float g2=S_gates[cur][b][2*Hn+h],g3=S_gates[cur][b][3*Hn+h];
      float cold = S_c[prev][b][h];
      float cn = sigm(g1)*cold + sigm(g0)*tanhf(g2);
      float hn = sigm(g3)*tanhf(cn);
      float hcv = clipv(hn);
      S_c[cur][b][h] = clipv(cn);
      S_h[cur][b][h] = hcv;
      sh.a.hc[h] = hcv;
    }
    __syncthreads();
    // itf = hc @ W_if + b_if (coalesced: lane j)
    if (tid < IFn){
      float acc = b_if[tid];
      for (int k=0;k<Hn;k+=8){
        float s = 0.f;
        #pragma unroll
        for (int u=0;u<8;u++) s += sh.a.hc[k+u]*W_if[(size_t)(k+u)*IFn + tid];
        acc += s;
      }
      sh.a.itf[tid] = acc;
      S_itf[b][tid] = acc;
    }
    __syncthreads();
    if (tid < WDn){
      sh.a.wkey[tid] = sh.a.itf[OFF_WKEY+tid];
      sh.a.er[tid]   = sigm(sh.a.itf[OFF_ERASE+tid]);
      sh.a.wv[tid]   = sh.a.itf[OFF_WVEC+tid];
    } else if (tid < WDn + Rn*WDn){
      int k2 = tid - WDn;
      sh.a.rk[k2>>6][k2&63] = sh.a.itf[OFF_RKEY + k2];
    }
    // usage update + stable-sort key
    {
      float fg0=sigm(sh.a.itf[OFF_FREE+0]), fg1=sigm(sh.a.itf[OFF_FREE+1]);
      float fg2=sigm(sh.a.itf[OFF_FREE+2]), fg3=sigm(sh.a.itf[OFF_FREE+3]);
      int n = tid;
      float uu = S_usage[prev][b][n], wwp = S_ww[prev][b][n];
      float u = uu + (1.f-uu)*wwp;
      float psi = (1.f - fg0*S_rw[b][0][n])*(1.f - fg1*S_rw[b][1][n])
                * (1.f - fg2*S_rw[b][2][n])*(1.f - fg3*S_rw[b][3][n]);
      float un = u*psi;
      S_usage[cur][b][n] = un;
      float v = EPSV + (1.f-EPSV)*un;
      sh.a.keys[n] = ((unsigned long long)__float_as_uint(v) << 32) | (unsigned)n;
    }
    __syncthreads();
    // key norms
    if (wvi==0){
      float kv = sh.a.wkey[lane];
      float s2 = wredsum(kv*kv);
      if (lane==0) sh.a.knw = sqrtf(s2);
    } else if (wvi<=4){
      int r = wvi-1;
      float kv = sh.a.rk[r][lane];
      float s2 = wredsum(kv*kv);
      if (lane==0) sh.a.knr[r] = sqrtf(s2);
    } else if (wvi==5 && lane<4){
      sh.a.betar[lane] = oneplusf(sh.a.itf[OFF_RSTR+lane]);
    }
    // sort-free allocation
    {
      unsigned long long myk = sh.a.keys[tid];
      float prod = 1.f;
      for (int j=0;j<Nn;j+=8){
        #pragma unroll
        for (int u=0;u<8;u++){
          unsigned long long kj = sh.a.keys[j+u];
          float uj = __uint_as_float((unsigned)(kj>>32));
          prod *= (kj < myk) ? uj : 1.f;
        }
      }
      float myu = __uint_as_float((unsigned)(myk>>32));
      sh.a.alloc[tid] = (1.f - myu)*prod;
    }
    __syncthreads();
    // write-content sims over OLD mem
    float betaw = oneplusf(sh.a.itf[OFF_WSTR]);
    for (int tile=0;tile<8;tile++){
      #pragma unroll
      for (int u=0;u<8;u++){
        int e = u*512 + tid;
        int nn = e>>6, w = e&63;
        sh.a.tile[nn][w] = S_mem[b][tile*64+nn][w];
      }
      __syncthreads();
      {
        int nn = tid>>3, qq = tid&7;
        float d=0.f, nrm=0.f;
        #pragma unroll
        for (int i=0;i<8;i++){
          int w = qq*8+i;
          float m = sh.a.tile[nn][w];
          d += m*sh.a.wkey[w]; nrm += m*m;
        }
        #pragma unroll
        for (int o=1;o<8;o<<=1){ d += __shfl_xor(d,o,64); nrm += __shfl_xor(nrm,o,64); }
        if (qq==0){
          int n = tile*64+nn;
          sh.a.sim[n] = betaw * d / (sh.a.knw*sqrtf(nrm) + EPSV);
        }
      }
      __syncthreads();
    }
    // softmax -> wc ; ww ; sumww
    {
      float v = sh.a.sim[tid];
      float mx = bredmax(v, sh.a.red);
      float e = expf(v - mx);
      float ssum = bredsum(e, sh.a.red);
      float wc = e/ssum;
      float ag = sigm(sh.a.itf[OFF_AG]);
      float wg = sigm(sh.a.itf[OFF_WG]);
      float wwv = wg*(ag*sh.a.alloc[tid] + (1.f-ag)*wc);
      S_ww[cur][b][tid] = wwv;
      float wsum = bredsum(wwv, sh.a.red);
      if (tid==0) S_sumww[b] = wsum;
      sh.a.alloc[tid] = wwv;     // alloc now holds ww
    }
    __syncthreads();
    if (tid==0) sig_release(&g_ww[b]);    // ---- link may start ----
    // mem erase/write + read-content sims on NEW mem
    for (int tile=0;tile<8;tile++){
      #pragma unroll
      for (int u=0;u<8;u++){
        int e = u*512 + tid;
        int nn = e>>6, w = e&63;
        int n = tile*64+nn;
        float m = S_mem[b][n][w];
        float wwn = sh.a.alloc[n];
        m = m*(1.f - wwn*sh.a.er[w]) + wwn*sh.a.wv[w];
        S_mem[b][n][w] = m;
        sh.a.tile[nn][w] = m;
      }
      __syncthreads();
      {
        int nn = tid>>3, qq = tid&7;
        float a0=0.f,a1=0.f,a2=0.f,a3=0.f,nrm=0.f;
        #pragma unroll
        for (int i=0;i<8;i++){
          int w = qq*8+i;
          float m = sh.a.tile[nn][w];
          a0 += m*sh.a.rk[0][w]; a1 += m*sh.a.rk[1][w];
          a2 += m*sh.a.rk[2][w]; a3 += m*sh.a.rk[3][w];
          nrm += m*m;
        }
        #pragma unroll
        for (int o=1;o<8;o<<=1){
          a0 += __shfl_xor(a0,o,64); a1 += __shfl_xor(a1,o,64);
          a2 += __shfl_xor(a2,o,64); a3 += __shfl_xor(a3,o,64);
          nrm += __shfl_xor(nrm,o,64);
        }
        if (qq==0){
          int n = tile*64+nn;
          float mn = sqrtf(nrm);
          sh.a.rsim[0][n] = sh.a.betar[0]*a0/(sh.a.knr[0]*mn + EPSV);
          sh.a.rsim[1][n] = sh.a.betar[1]*a1/(sh.a.knr[1]*mn + EPSV);
          sh.a.rsim[2][n] = sh.a.betar[2]*a2/(sh.a.knr[2]*mn + EPSV);
          sh.a.rsim[3][n] = sh.a.betar[3]*a3/(sh.a.knr[3]*mn + EPSV);
        }
      }
      __syncthreads();
    }
    // rc softmax per head
    for (int r=0;r<Rn;r++){
      float v = sh.a.rsim[r][tid];
      float mx = bredmax(v, sh.a.red);
      float e = expf(v - mx);
      float ssum = bredsum(e, sh.a.red);
      S_rc[b][r][tid] = e/ssum;
    }
    __syncthreads();
    if (tid==0) sig_release(&g_rc[b]);

  } else if (bid < 288){
    // ================= link =================
    const int idx = bid - 32;
    const int b = idx >> 3, ch = idx & 7;
    const int i0 = ch*64;
    if (tid==0){
      spin_until(&g_ww[b], (unsigned)(t+1));
      __builtin_amdgcn_fence(__ATOMIC_ACQUIRE, "agent");
    }
    __syncthreads();
    sh.l.ww[tid]   = S_ww[cur][b][tid];
    sh.l.prec[tid] = S_prec[prev][b][tid];
    for (int k=tid;k<Rn*Nn;k+=512) ((float*)sh.l.rw)[k] = ((const float*)S_rw[b])[k];
    __syncthreads();
    float sumww = S_sumww[b];
    float wj[2][4], pj[2][4], rj[4][2][4];
    #pragma unroll
    for (int jjc=0;jjc<2;jjc++){
      float4 w4 = ((const float4*)sh.l.ww)[jjc*64+lane];
      float4 p4 = ((const float4*)sh.l.prec)[jjc*64+lane];
      wj[jjc][0]=w4.x; wj[jjc][1]=w4.y; wj[jjc][2]=w4.z; wj[jjc][3]=w4.w;
      pj[jjc][0]=p4.x; pj[jjc][1]=p4.y; pj[jjc][2]=p4.z; pj[jjc][3]=p4.w;
      #pragma unroll
      for (int r=0;r<4;r++){
        float4 r4 = ((const float4*)sh.l.rw[r])[jjc*64+lane];
        rj[r][jjc][0]=r4.x; rj[r][jjc][1]=r4.y; rj[r][jjc][2]=r4.z; rj[r][jjc][3]=r4.w;
      }
    }
    float bwa[4][2][4];
    #pragma unroll
    for (int r=0;r<4;r++)
      #pragma unroll
      for (int jjc=0;jjc<2;jjc++)
        #pragma unroll
        for (int s=0;s<4;s++) bwa[r][jjc][s]=0.f;
    for (int rr=0;rr<8;rr++){
      const int i = i0 + wvi*8 + rr;
      float wi = sh.l.ww[i];
      float ci = 1.f - wi;
      float ri[4] = {sh.l.rw[0][i], sh.l.rw[1][i], sh.l.rw[2][i], sh.l.rw[3][i]};
      float f[4] = {0.f,0.f,0.f,0.f};
      float4* lrow4 = (float4*)(&S_link[b][i][0]);
      #pragma unroll
      for (int jjc=0;jjc<2;jjc++){
        float4 L4 = lrow4[jjc*64+lane];
        float Ls[4] = {L4.x, L4.y, L4.z, L4.w};
        #pragma unroll
        for (int s=0;s<4;s++){
          float Ln = (ci - wj[jjc][s])*Ls[s] + wi*pj[jjc][s];
          int j = jjc*256 + lane*4 + s;
          Ln = (j==i) ? 0.f : Ln;
          Ls[s] = Ln;
          #pragma unroll
          for (int r=0;r<4;r++){
            f[r] += Ln*rj[r][jjc][s];
            bwa[r][jjc][s] += Ln*ri[r];
          }
        }
        float4 Lo; Lo.x=Ls[0]; Lo.y=Ls[1]; Lo.z=Ls[2]; Lo.w=Ls[3];
        lrow4[jjc*64+lane] = Lo;
      }
      #pragma unroll
      for (int r=0;r<4;r++){
        float fr = wredsum(f[r]);
        if (lane==0) S_fw[b][r][i] = fr;
      }
    }
    if (wvi < 4){
      #pragma unroll
      for (int r=0;r<4;r++)
        #pragma unroll
        for (int jjc=0;jjc<2;jjc++){
          float4 v4; v4.x=bwa[r][jjc][0]; v4.y=bwa[r][jjc][1]; v4.z=bwa[r][jjc][2]; v4.w=bwa[r][jjc][3];
          ((float4*)sh.l.bwp4[wvi][r])[jjc*64+lane] = v4;
        }
    }
    __syncthreads();
    if (wvi >= 4){
      int v = wvi-4;
      #pragma unroll
      for (int r=0;r<4;r++)
        #pragma unroll
        for (int jjc=0;jjc<2;jjc++){
          float4 v4 = ((float4*)sh.l.bwp4[v][r])[jjc*64+lane];
          v4.x+=bwa[r][jjc][0]; v4.y+=bwa[r][jjc][1]; v4.z+=bwa[r][jjc][2]; v4.w+=bwa[r][jjc][3];
          ((float4*)sh.l.bwp4[v][r])[jjc*64+lane] = v4;
        }
    }
    __syncthreads();
    for (int k=tid;k<Rn*Nn;k+=512){
      float s = ((float*)sh.l.bwp4[0])[k] + ((float*)sh.l.bwp4[1])[k]
              + ((float*)sh.l.bwp4[2])[k] + ((float*)sh.l.bwp4[3])[k];
      S_bwp[b][ch][k] = s;
    }
    if (tid < 64){
      int j = i0 + tid;
      S_prec[cur][b][j] = (1.f - sumww)*sh.l.prec[j] + sh.l.ww[j];
    }
    __syncthreads();
    if (tid==0) sig_release(&g_ld[b]);

  } else if (bid < 320){
    // ================= finalize =================
    const int b = bid - 288;
    if (tid==0){
      spin_until(&g_ld[b], 8u*(unsigned)(t+1));
      spin_until(&g_rc[b], (unsigned)(t+1));
      __builtin_amdgcn_fence(__ATOMIC_ACQUIRE, "agent");
    }
    __syncthreads();
    for (int k=tid;k<Rn*Nn;k+=512){
      ((float*)sh.f.fw)[k] = ((const float*)S_fw[b])[k];
      float sbw = 0.f;
      #pragma unroll
      for (int ch=0;ch<8;ch++) sbw += S_bwp[b][ch][k];
      ((float*)sh.f.bw)[k] = sbw;
      ((float*)sh.f.rc)[k] = ((const float*)S_rc[b])[k];
    }
    if (tid < 4){
      int r = tid;
      float m0 = S_itf[b][OFF_MODES + r*3 + 0];
      float m1 = S_itf[b][OFF_MODES + r*3 + 1];
      float m2 = S_itf[b][OFF_MODES + r*3 + 2];
      float mx = fmaxf(m0,fmaxf(m1,m2));
      float e0=expf(m0-mx), e1=expf(m1-mx), e2=expf(m2-mx);
      float si = e0+e1+e2;
      sh.f.modes[r][0]=e0/si; sh.f.modes[r][1]=e1/si; sh.f.modes[r][2]=e2/si;
    }
    __syncthreads();
    for (int k=tid;k<Rn*Nn;k+=512){
      int r = k>>9, n = k&511;
      float v = sh.f.modes[r][2]*sh.f.rc[r][n] + sh.f.modes[r][1]*sh.f.fw[r][n]
              + sh.f.modes[r][0]*sh.f.bw[r][n];
      sh.f.rc[r][n] = v;
      S_rw[b][r][n] = v;
    }
    __syncthreads();
    {
      float a0=0.f,a1=0.f,a2=0.f,a3=0.f;
      #pragma unroll 4
      for (int nn=0;nn<64;nn++){
        int n = wvi*64+nn;
        float m = S_mem[b][n][lane];
        a0 += sh.f.rc[0][n]*m; a1 += sh.f.rc[1][n]*m;
        a2 += sh.f.rc[2][n]*m; a3 += sh.f.rc[3][n]*m;
      }
      sh.f.part[wvi][0][lane]=a0; sh.f.part[wvi][1][lane]=a1;
      sh.f.part[wvi][2][lane]=a2; sh.f.part[wvi][3][lane]=a3;
    }
    __syncthreads();
    if (tid < 256){
      int r = tid>>6, w = tid&63;
      float sv = 0.f;
      #pragma unroll
      for (int v=0;v<8;v++) sv += sh.f.part[v][r][w];
      S_reads[b][r][w] = sv;
      sh.f.vin[256+tid] = sv;
      sh.f.vin[tid] = S_h[cur][b][tid];
    }
    __syncthreads();
    {
      int qq = tid>>6, o = tid&63;
      float sacc = 0.f;
      for (int k2=qq*64;k2<qq*64+64;k2+=8){
        #pragma unroll
        for (int u=0;u<8;u++) sacc += sh.f.vin[k2+u]*W_out[(size_t)(k2+u)*OUTn + o];
      }
      sh.f.part[qq][0][o] = sacc;
    }
    __syncthreads();
    if (tid < 64){
      float sv = b_out[tid];
      #pragma unroll
      for (int qq=0;qq<8;qq++) sv += sh.f.part[qq][0][tid];
      outp[((size_t)t*Bn + b)*OUTn + tid] = clipv(sv);
    }
    __syncthreads();
    if (tid==0) sig_release(&g_fin);

  } else {
    // ================= gates for step t+1 =================
    if (t+1 >= Tn) return;
    const int jt = bid - 320;
    if (tid==0){
      spin_until(&g_fin, 32u*(unsigned)(t+1));
      __builtin_amdgcn_fence(__ATOMIC_ACQUIRE, "agent");
    }
    __syncthreads();
    gates_core(sh.g, t+1, jt, xin, Wx, Wh, b_lstm);
  }
}

extern "C" void kernel_launch(void* const* d_in, const int* in_sizes, int n_in,
                              void* d_out, int out_size, void* d_ws, size_t ws_size,
                              hipStream_t stream){
  (void)in_sizes; (void)n_in; (void)d_ws; (void)ws_size; (void)out_size;
  const float* xin = (const float*)d_in[0];
  const float* Wx  = (const float*)d_in[1];
  const float* Wh  = (const float*)d_in[2];
  const float* bl  = (const float*)d_in[3];
  const float* Wif = (const float*)d_in[4];
  const float* bif = (const float*)d_in[5];
  const float* Wo  = (const float*)d_in[6];
  const float* bo  = (const float*)d_in[7];
  hipLaunchKernelGGL(k_init, dim3(1024), dim3(256), 0, stream);
  hipLaunchKernelGGL(k_gates_pro, dim3(16), dim3(512), 0, stream, xin, Wx, Wh, bl);
  for (int t=0; t<Tn; ++t){
    hipLaunchKernelGGL(k_step, dim3(336), dim3(512), 0, stream,
                       t, xin, Wx, Wh, bl, Wif, bif, Wo, bo, (float*)d_out);
  }
}